// Round 1
// baseline (951.743 us; speedup 1.0000x reference)
//
#include <hip/hip_runtime.h>
#include <math.h>

#define B_N 2048
#define V_N 5023
#define L_N 150
#define V3_N 15069
#define BSTR 192   // betas_ext row stride (150 betas + 36 pose_feat + pad)

// workspace offsets (in floats)
#define OFF_PART 0          // 40 * 2280 = 91200
#define OFF_SJ   98304      // 5 * 456 = 2280
#define OFF_BEXT 131072     // 2048 * 192 = 393216
#define OFF_JTS  524288     // 2048 * 16 = 32768
#define OFF_A    557056     // 2048 * 64 = 131072
// total needed: 688128 floats = 2.63 MB

// ---------------- K1: partial SJ[j][c] = sum_v Jr[j,v] * col_c(v) ----------------
// columns 0..449 = shapedirs flat (k*150+l), 450..452 = v_template
__global__ __launch_bounds__(256) void k_sj_part(const float* __restrict__ sdirs,
                                                 const float* __restrict__ vtemp,
                                                 const float* __restrict__ Jr,
                                                 float* __restrict__ ws) {
  __shared__ float JrL[5][128];
  int t = threadIdx.x, bk = blockIdx.x;
  int vstart = bk * 126;
  int vend = min(vstart + 126, V_N);
  int cnt = vend - vstart;
  for (int idx = t; idx < 5 * 126; idx += 256) {
    int j = idx / 126, vi = idx - j * 126;
    JrL[j][vi] = (vi < cnt) ? Jr[j * V_N + vstart + vi] : 0.0f;
  }
  __syncthreads();
  float acc0[5] = {0, 0, 0, 0, 0}, acc1[5] = {0, 0, 0, 0, 0};
  int c0 = t, c1 = t + 256;
  for (int vi = 0; vi < cnt; ++vi) {
    int v = vstart + vi;
    float val0 = sdirs[v * 450 + c0];  // c0 < 256 < 450 always
    float val1 = 0.0f;
    if (c1 < 450) val1 = sdirs[v * 450 + c1];
    else if (c1 < 453) val1 = vtemp[v * 3 + (c1 - 450)];
#pragma unroll
    for (int j = 0; j < 5; ++j) {
      float w = JrL[j][vi];
      acc0[j] = fmaf(w, val0, acc0[j]);
      acc1[j] = fmaf(w, val1, acc1[j]);
    }
  }
  float* part = ws + OFF_PART + (size_t)bk * 2280;
#pragma unroll
  for (int j = 0; j < 5; ++j) {
    part[j * 456 + c0] = acc0[j];
    if (c1 < 453) part[j * 456 + c1] = acc1[j];
  }
}

// ---------------- K1b: reduce 40 partials ----------------
__global__ void k_sj_reduce(float* __restrict__ ws) {
  int id = blockIdx.x * 256 + threadIdx.x;
  if (id >= 2280) return;
  int c = id % 456;
  if (c >= 453) return;  // never written slots
  float s = 0.0f;
  for (int bk = 0; bk < 40; ++bk) s += ws[OFF_PART + (size_t)bk * 2280 + id];
  ws[OFF_SJ + id] = s;
}

// ---------------- K2a: Jts[b,j,k] = SJ_vt + betas . SJ ----------------
__global__ void k_jts(const float* __restrict__ shp, const float* __restrict__ expr,
                      float* __restrict__ ws) {
  int gid = blockIdx.x * 256 + threadIdx.x;
  int b = gid >> 4, jk = gid & 15;
  if (b >= B_N || jk >= 15) return;
  int j = jk / 3, k = jk - j * 3;
  const float* SJ = ws + OFF_SJ + j * 456;
  float acc = SJ[450 + k];
  const float* srow = shp + (size_t)b * 100;
  const float* erow = expr + (size_t)b * 50;
  for (int l = 0; l < 100; ++l) acc = fmaf(srow[l], SJ[k * 150 + l], acc);
  for (int l = 0; l < 50; ++l) acc = fmaf(erow[l], SJ[k * 150 + 100 + l], acc);
  ws[OFF_JTS + (size_t)b * 16 + jk] = acc;
}

// ---------------- K2a2: fill betas_ext[b][0..149], zero rest ----------------
__global__ void k_bext(const float* __restrict__ shp, const float* __restrict__ expr,
                       float* __restrict__ ws) {
  int idx = blockIdx.x * 256 + threadIdx.x;
  if (idx >= B_N * BSTR) return;
  int b = idx / BSTR, c = idx - b * BSTR;
  float v = 0.0f;
  if (c < 100) v = shp[(size_t)b * 100 + c];
  else if (c < 150) v = expr[(size_t)b * 50 + (c - 100)];
  ws[OFF_BEXT + idx] = v;
}

// ---------------- K2b: Rodrigues + kinematic chain + rel transforms ----------------
__global__ void k_pose(const float* __restrict__ pose, float* __restrict__ ws,
                       float* __restrict__ out) {
  int b = blockIdx.x * 256 + threadIdx.x;
  if (b >= B_N) return;
  float R[5][3][3];
#pragma unroll
  for (int j = 0; j < 5; ++j) {
    float rx = pose[(size_t)b * 15 + j * 3 + 0];
    float ry = pose[(size_t)b * 15 + j * 3 + 1];
    float rz = pose[(size_t)b * 15 + j * 3 + 2];
    float sx = rx + 1e-8f, sy = ry + 1e-8f, sz = rz + 1e-8f;
    float ang = sqrtf(sx * sx + sy * sy + sz * sz);
    float inv = 1.0f / ang;
    float ux = rx * inv, uy = ry * inv, uz = rz * inv;
    float c = cosf(ang), s = sinf(ang), omc = 1.0f - c;
    float K[3][3] = {{0.0f, -uz, uy}, {uz, 0.0f, -ux}, {-uy, ux, 0.0f}};
#pragma unroll
    for (int m = 0; m < 3; ++m)
#pragma unroll
      for (int n = 0; n < 3; ++n) {
        float k2 = 0.0f;
#pragma unroll
        for (int q = 0; q < 3; ++q) k2 += K[m][q] * K[q][n];
        R[j][m][n] = ((m == n) ? 1.0f : 0.0f) + s * K[m][n] + omc * k2;
      }
  }
  // pose_feature -> betas_ext[b][150..185]
  float* bx = ws + OFF_BEXT + (size_t)b * BSTR + 150;
#pragma unroll
  for (int j = 1; j < 5; ++j)
#pragma unroll
    for (int m = 0; m < 3; ++m)
#pragma unroll
      for (int n = 0; n < 3; ++n)
        bx[(j - 1) * 9 + m * 3 + n] = R[j][m][n] - ((m == n) ? 1.0f : 0.0f);
  // joints
  float Jt[5][3];
#pragma unroll
  for (int j = 0; j < 5; ++j)
#pragma unroll
    for (int k = 0; k < 3; ++k) Jt[j][k] = ws[OFF_JTS + (size_t)b * 16 + j * 3 + k];
  const int par[5] = {0, 0, 1, 1, 1};
  float rel[5][3];
#pragma unroll
  for (int k = 0; k < 3; ++k) rel[0][k] = Jt[0][k];
#pragma unroll
  for (int j = 1; j < 5; ++j)
#pragma unroll
    for (int k = 0; k < 3; ++k) rel[j][k] = Jt[j][k] - Jt[par[j]][k];
  float Rg[5][3][3], tg[5][3];
#pragma unroll
  for (int m = 0; m < 3; ++m) {
#pragma unroll
    for (int n = 0; n < 3; ++n) Rg[0][m][n] = R[0][m][n];
    tg[0][m] = rel[0][m];
  }
#pragma unroll
  for (int j = 1; j < 5; ++j) {
    int p = par[j];
#pragma unroll
    for (int m = 0; m < 3; ++m) {
      float t = tg[p][m];
#pragma unroll
      for (int n = 0; n < 3; ++n) {
        float s = 0.0f;
#pragma unroll
        for (int q = 0; q < 3; ++q) s = fmaf(Rg[p][m][q], R[j][q][n], s);
        Rg[j][m][n] = s;
        t = fmaf(Rg[p][m][n], rel[j][n], t);
      }
      tg[j][m] = t;
    }
  }
  // posed_joints output
#pragma unroll
  for (int j = 0; j < 5; ++j)
#pragma unroll
    for (int k = 0; k < 3; ++k)
      out[(size_t)B_N * V_N * 3 + ((size_t)b * 5 + j) * 3 + k] = tg[j][k];
  // rel transforms A[b][j][3][4]
  float* A = ws + OFF_A + (size_t)b * 64;
#pragma unroll
  for (int j = 0; j < 5; ++j)
#pragma unroll
    for (int m = 0; m < 3; ++m) {
      float tj = 0.0f;
#pragma unroll
      for (int n = 0; n < 3; ++n) {
        A[j * 12 + m * 4 + n] = Rg[j][m][n];
        tj = fmaf(Rg[j][m][n], Jt[j][n], tj);
      }
      A[j * 12 + m * 4 + 3] = tg[j][m] - tj;
    }
}

// ---------------- K3: fused v_shaped + pose_offsets + skinning ----------------
__global__ __launch_bounds__(256) void k_verts(const float* __restrict__ sdirs,
                                               const float* __restrict__ pdirs,
                                               const float* __restrict__ vtemp,
                                               const float* __restrict__ lw,
                                               const float* __restrict__ ws,
                                               float* __restrict__ out) {
  const float* bext = ws + OFF_BEXT;
  const float* Aw = ws + OFF_A;
  int t = threadIdx.x;
  int vl = t & 63;
  int wq = __builtin_amdgcn_readfirstlane(t >> 6);  // wave-uniform in SGPR
  int v = blockIdx.x * 64 + vl;
  int b0 = blockIdx.y * 32 + wq * 8;
  if (v >= V_N) return;
  float acc[8][3];
#pragma unroll
  for (int i = 0; i < 8; ++i)
#pragma unroll
    for (int k = 0; k < 3; ++k) acc[i][k] = 0.0f;
  const float* sp = sdirs + (size_t)v * 450;
  const float* brow = bext + (size_t)b0 * BSTR;
  // shape/expression blendshapes, K=150
  for (int l = 0; l < 150; l += 2) {
    float2 s0 = *reinterpret_cast<const float2*>(sp + l);
    float2 s1 = *reinterpret_cast<const float2*>(sp + 150 + l);
    float2 s2 = *reinterpret_cast<const float2*>(sp + 300 + l);
#pragma unroll
    for (int i = 0; i < 8; ++i) {
      float be0 = brow[i * BSTR + l];
      float be1 = brow[i * BSTR + l + 1];
      acc[i][0] = fmaf(s0.x, be0, fmaf(s0.y, be1, acc[i][0]));
      acc[i][1] = fmaf(s1.x, be0, fmaf(s1.y, be1, acc[i][1]));
      acc[i][2] = fmaf(s2.x, be0, fmaf(s2.y, be1, acc[i][2]));
    }
  }
  // pose blendshapes, K=36
  const float* pp = pdirs + (size_t)3 * v;
  for (int p = 0; p < 36; ++p) {
    float d0 = pp[(size_t)p * V3_N + 0];
    float d1 = pp[(size_t)p * V3_N + 1];
    float d2 = pp[(size_t)p * V3_N + 2];
#pragma unroll
    for (int i = 0; i < 8; ++i) {
      float pf = brow[i * BSTR + 150 + p];
      acc[i][0] = fmaf(d0, pf, acc[i][0]);
      acc[i][1] = fmaf(d1, pf, acc[i][1]);
      acc[i][2] = fmaf(d2, pf, acc[i][2]);
    }
  }
  float vt0 = vtemp[(size_t)v * 3 + 0];
  float vt1 = vtemp[(size_t)v * 3 + 1];
  float vt2 = vtemp[(size_t)v * 3 + 2];
  float w[5];
#pragma unroll
  for (int j = 0; j < 5; ++j) w[j] = lw[(size_t)v * 5 + j];
#pragma unroll
  for (int i = 0; i < 8; ++i) {
    const float* Ab = Aw + (size_t)(b0 + i) * 64;
    float T[12];
#pragma unroll
    for (int mn = 0; mn < 12; ++mn) {
      float s = w[0] * Ab[mn];
#pragma unroll
      for (int j = 1; j < 5; ++j) s = fmaf(w[j], Ab[j * 12 + mn], s);
      T[mn] = s;
    }
    float x = acc[i][0] + vt0, y = acc[i][1] + vt1, z = acc[i][2] + vt2;
    float ox = fmaf(T[0], x, fmaf(T[1], y, fmaf(T[2], z, T[3])));
    float oy = fmaf(T[4], x, fmaf(T[5], y, fmaf(T[6], z, T[7])));
    float oz = fmaf(T[8], x, fmaf(T[9], y, fmaf(T[10], z, T[11])));
    size_t o = ((size_t)(b0 + i) * V_N + v) * 3;
    out[o + 0] = ox;
    out[o + 1] = oy;
    out[o + 2] = oz;
  }
}

extern "C" void kernel_launch(void* const* d_in, const int* in_sizes, int n_in,
                              void* d_out, int out_size, void* d_ws, size_t ws_size,
                              hipStream_t stream) {
  const float* shp = (const float*)d_in[0];
  const float* expr = (const float*)d_in[1];
  const float* pose = (const float*)d_in[2];
  const float* vtemp = (const float*)d_in[3];
  const float* sdirs = (const float*)d_in[4];
  const float* pdirs = (const float*)d_in[5];
  const float* Jr = (const float*)d_in[6];
  const float* lw = (const float*)d_in[7];
  float* out = (float*)d_out;
  float* ws = (float*)d_ws;

  hipLaunchKernelGGL(k_sj_part, dim3(40), dim3(256), 0, stream, sdirs, vtemp, Jr, ws);
  hipLaunchKernelGGL(k_sj_reduce, dim3(9), dim3(256), 0, stream, ws);
  hipLaunchKernelGGL(k_jts, dim3(128), dim3(256), 0, stream, shp, expr, ws);
  hipLaunchKernelGGL(k_bext, dim3((B_N * BSTR + 255) / 256), dim3(256), 0, stream, shp, expr, ws);
  hipLaunchKernelGGL(k_pose, dim3(8), dim3(256), 0, stream, pose, ws, out);
  hipLaunchKernelGGL(k_verts, dim3((V_N + 63) / 64, B_N / 32), dim3(256), 0, stream,
                     sdirs, pdirs, vtemp, lw, ws, out);
}

// Round 2
// 293.746 us; speedup vs baseline: 3.2400x; 3.2400x over previous
//
#include <hip/hip_runtime.h>
#include <math.h>

#define B_N 2048
#define V_N 5023
#define V3_N 15069
#define BSTR 192
#define NSJB 157
#define CHUNK 32

// ---------------- K1: partial SJ[j][c] = sum_v Jr[j,v] * col_c(v) ----------------
// columns 0..449 = shapedirs flat (k*150+l), 450..452 = v_template
__global__ __launch_bounds__(256) void k_sj_part(const float* __restrict__ sdirs,
                                                 const float* __restrict__ vtemp,
                                                 const float* __restrict__ Jr,
                                                 float* __restrict__ part) {
  __shared__ float JrL[5][CHUNK];
  int t = threadIdx.x, bk = blockIdx.x;
  int vstart = bk * CHUNK;
  int cnt = min(CHUNK, V_N - vstart);
  for (int idx = t; idx < 5 * CHUNK; idx += 256) {
    int j = idx / CHUNK, vi = idx % CHUNK;
    JrL[j][vi] = (vi < cnt) ? Jr[j * V_N + vstart + vi] : 0.0f;
  }
  __syncthreads();
  float acc0[5] = {0, 0, 0, 0, 0}, acc1[5] = {0, 0, 0, 0, 0};
  int c0 = t, c1 = t + 256;
#pragma unroll 4
  for (int vi = 0; vi < CHUNK; ++vi) {
    int v = min(vstart + vi, V_N - 1);
    float val0 = sdirs[(size_t)v * 450 + c0];
    float val1 = 0.0f;
    if (c1 < 450) val1 = sdirs[(size_t)v * 450 + c1];
    else if (c1 < 453) val1 = vtemp[(size_t)v * 3 + (c1 - 450)];
#pragma unroll
    for (int j = 0; j < 5; ++j) {
      float w = JrL[j][vi];
      acc0[j] = fmaf(w, val0, acc0[j]);
      acc1[j] = fmaf(w, val1, acc1[j]);
    }
  }
  float* prow = part + (size_t)bk * 2280;
#pragma unroll
  for (int j = 0; j < 5; ++j) {
    prow[j * 456 + c0] = acc0[j];
    if (c1 < 453) prow[j * 456 + c1] = acc1[j];
  }
}

// ---------------- K1b: reduce partials ----------------
__global__ void k_sj_reduce(const float* __restrict__ part, float* __restrict__ SJ) {
  int id = blockIdx.x * 256 + threadIdx.x;
  if (id >= 2280) return;
  int c = id % 456;
  if (c >= 453) return;
  float s = 0.0f;
  for (int bk = 0; bk < NSJB; ++bk) s += part[(size_t)bk * 2280 + id];
  SJ[id] = s;
}

// ---------------- K2a: Jts[b,j,k] = SJ_vt + betas . SJ ----------------
__global__ void k_jts(const float* __restrict__ shp, const float* __restrict__ expr,
                      const float* __restrict__ SJ, float* __restrict__ Jts) {
  int gid = blockIdx.x * 256 + threadIdx.x;
  int b = gid >> 4, jk = gid & 15;
  if (b >= B_N || jk >= 15) return;
  int j = jk / 3, k = jk - j * 3;
  const float* SJr = SJ + j * 456;
  float acc = SJr[450 + k];
  const float* srow = shp + (size_t)b * 100;
  const float* erow = expr + (size_t)b * 50;
  for (int l = 0; l < 100; ++l) acc = fmaf(srow[l], SJr[k * 150 + l], acc);
  for (int l = 0; l < 50; ++l) acc = fmaf(erow[l], SJr[k * 150 + 100 + l], acc);
  Jts[(size_t)b * 16 + jk] = acc;
}

// ---------------- K2a2: fill bext[b][0..149], zero rest ----------------
__global__ void k_bext(const float* __restrict__ shp, const float* __restrict__ expr,
                       float* __restrict__ bext) {
  int idx = blockIdx.x * 256 + threadIdx.x;
  if (idx >= B_N * BSTR) return;
  int b = idx / BSTR, c = idx - b * BSTR;
  float v = 0.0f;
  if (c < 100) v = shp[(size_t)b * 100 + c];
  else if (c < 150) v = expr[(size_t)b * 50 + (c - 100)];
  bext[idx] = v;
}

// ---------------- K2b: Rodrigues + kinematic chain + rel transforms ----------------
__global__ void k_pose(const float* __restrict__ pose, const float* __restrict__ Jts,
                       float* __restrict__ bext, float* __restrict__ A,
                       float* __restrict__ out) {
  int b = blockIdx.x * 256 + threadIdx.x;
  if (b >= B_N) return;
  float R[5][3][3];
#pragma unroll
  for (int j = 0; j < 5; ++j) {
    float rx = pose[(size_t)b * 15 + j * 3 + 0];
    float ry = pose[(size_t)b * 15 + j * 3 + 1];
    float rz = pose[(size_t)b * 15 + j * 3 + 2];
    float sx = rx + 1e-8f, sy = ry + 1e-8f, sz = rz + 1e-8f;
    float ang = sqrtf(sx * sx + sy * sy + sz * sz);
    float inv = 1.0f / ang;
    float ux = rx * inv, uy = ry * inv, uz = rz * inv;
    float c = cosf(ang), s = sinf(ang), omc = 1.0f - c;
    float K[3][3] = {{0.0f, -uz, uy}, {uz, 0.0f, -ux}, {-uy, ux, 0.0f}};
#pragma unroll
    for (int m = 0; m < 3; ++m)
#pragma unroll
      for (int n = 0; n < 3; ++n) {
        float k2 = 0.0f;
#pragma unroll
        for (int q = 0; q < 3; ++q) k2 += K[m][q] * K[q][n];
        R[j][m][n] = ((m == n) ? 1.0f : 0.0f) + s * K[m][n] + omc * k2;
      }
  }
  float* bx = bext + (size_t)b * BSTR + 150;
#pragma unroll
  for (int j = 1; j < 5; ++j)
#pragma unroll
    for (int m = 0; m < 3; ++m)
#pragma unroll
      for (int n = 0; n < 3; ++n)
        bx[(j - 1) * 9 + m * 3 + n] = R[j][m][n] - ((m == n) ? 1.0f : 0.0f);
  float Jt[5][3];
#pragma unroll
  for (int j = 0; j < 5; ++j)
#pragma unroll
    for (int k = 0; k < 3; ++k) Jt[j][k] = Jts[(size_t)b * 16 + j * 3 + k];
  const int par[5] = {0, 0, 1, 1, 1};
  float rel[5][3];
#pragma unroll
  for (int k = 0; k < 3; ++k) rel[0][k] = Jt[0][k];
#pragma unroll
  for (int j = 1; j < 5; ++j)
#pragma unroll
    for (int k = 0; k < 3; ++k) rel[j][k] = Jt[j][k] - Jt[par[j]][k];
  float Rg[5][3][3], tg[5][3];
#pragma unroll
  for (int m = 0; m < 3; ++m) {
#pragma unroll
    for (int n = 0; n < 3; ++n) Rg[0][m][n] = R[0][m][n];
    tg[0][m] = rel[0][m];
  }
#pragma unroll
  for (int j = 1; j < 5; ++j) {
    int p = par[j];
#pragma unroll
    for (int m = 0; m < 3; ++m) {
      float t = tg[p][m];
#pragma unroll
      for (int n = 0; n < 3; ++n) {
        float s = 0.0f;
#pragma unroll
        for (int q = 0; q < 3; ++q) s = fmaf(Rg[p][m][q], R[j][q][n], s);
        Rg[j][m][n] = s;
        t = fmaf(Rg[p][m][n], rel[j][n], t);
      }
      tg[j][m] = t;
    }
  }
#pragma unroll
  for (int j = 0; j < 5; ++j)
#pragma unroll
    for (int k = 0; k < 3; ++k)
      out[(size_t)B_N * V_N * 3 + ((size_t)b * 5 + j) * 3 + k] = tg[j][k];
  float* Ab = A + (size_t)b * 64;
#pragma unroll
  for (int j = 0; j < 5; ++j)
#pragma unroll
    for (int m = 0; m < 3; ++m) {
      float tj = 0.0f;
#pragma unroll
      for (int n = 0; n < 3; ++n) {
        Ab[j * 12 + m * 4 + n] = Rg[j][m][n];
        tj = fmaf(Rg[j][m][n], Jt[j][n], tj);
      }
      Ab[j * 12 + m * 4 + 3] = tg[j][m] - tj;
    }
}

// ---------------- K_trans: shapedirs [V][3][150] -> BT [150][V*3] ----------------
__global__ __launch_bounds__(256) void k_trans(const float* __restrict__ sdirs,
                                               float* __restrict__ BT) {
  __shared__ float S[16][451];
  int t = threadIdx.x;
  int v0 = blockIdx.x * 16;
  int nv = min(16, V_N - v0);
  for (int idx = t; idx < nv * 450; idx += 256) {
    int row = idx / 450, col = idx - row * 450;
    S[row][col] = sdirs[(size_t)(v0 + row) * 450 + col];
  }
  __syncthreads();
  int nc = nv * 3;
  for (int widx = t; widx < 150 * nc; widx += 256) {
    int l = widx / nc, c = widx - l * nc;
    int row = c / 3, k = c - row * 3;
    BT[(size_t)l * V3_N + (size_t)v0 * 3 + c] = S[row][k * 150 + l];
  }
}

// ---------------- K3: fused blendshapes + skinning (coalesced basis) ----------------
__global__ __launch_bounds__(256) void k_verts2(const float* __restrict__ BT,
                                                const float* __restrict__ pdirs,
                                                const float* __restrict__ vtemp,
                                                const float* __restrict__ lw,
                                                const float* __restrict__ bext,
                                                const float* __restrict__ A,
                                                float* __restrict__ out) {
  __shared__ alignas(16) float Lb[186][32];
  int t = threadIdx.x;
  int bid = blockIdx.x;
  int xb = bid >> 6;   // vertex tile (slow)
  int yb = bid & 63;   // batch tile (fast) -> L2 reuse of basis slice
  int lane = t & 63;
  int wq = __builtin_amdgcn_readfirstlane(t >> 6);
  int v = xb * 64 + lane;
  int vv = v < V_N ? v : V_N - 1;
  // stage 32 batches x 186 coeffs into LDS (conflict-free writes)
  for (int idx = t; idx < 186 * 32; idx += 256) {
    int i = idx & 31, l = idx >> 5;
    Lb[l][i] = bext[(size_t)(yb * 32 + i) * BSTR + l];
  }
  __syncthreads();
  int i0 = wq * 8;
  float acc[8][3];
#pragma unroll
  for (int i = 0; i < 8; ++i)
#pragma unroll
    for (int k = 0; k < 3; ++k) acc[i][k] = 0.0f;

#define BODY(BASEPTR, LROW)                                                 \
  {                                                                         \
    float4 ba = *reinterpret_cast<const float4*>(&Lb[LROW][i0]);            \
    float4 bb = *reinterpret_cast<const float4*>(&Lb[LROW][i0 + 4]);        \
    const float* base_ = (BASEPTR);                                         \
    float d0 = base_[0], d1 = base_[1], d2 = base_[2];                      \
    float bvs[8] = {ba.x, ba.y, ba.z, ba.w, bb.x, bb.y, bb.z, bb.w};        \
    _Pragma("unroll") for (int i = 0; i < 8; ++i) {                         \
      acc[i][0] = fmaf(d0, bvs[i], acc[i][0]);                              \
      acc[i][1] = fmaf(d1, bvs[i], acc[i][1]);                              \
      acc[i][2] = fmaf(d2, bvs[i], acc[i][2]);                              \
    }                                                                       \
  }

  const float* bp = BT + (size_t)3 * vv;
#pragma unroll 2
  for (int l = 0; l < 150; ++l) BODY(bp + (size_t)l * V3_N, l)
  const float* pp = pdirs + (size_t)3 * vv;
#pragma unroll 2
  for (int p = 0; p < 36; ++p) BODY(pp + (size_t)p * V3_N, 150 + p)
#undef BODY

  float vt0 = vtemp[(size_t)vv * 3 + 0];
  float vt1 = vtemp[(size_t)vv * 3 + 1];
  float vt2 = vtemp[(size_t)vv * 3 + 2];
  float w[5];
#pragma unroll
  for (int j = 0; j < 5; ++j) w[j] = lw[(size_t)vv * 5 + j];
  int b0 = yb * 32 + i0;
#pragma unroll
  for (int i = 0; i < 8; ++i) {
    const float* Ab = A + (size_t)(b0 + i) * 64;
    float T[12];
#pragma unroll
    for (int mn = 0; mn < 12; ++mn) {
      float s = w[0] * Ab[mn];
#pragma unroll
      for (int j = 1; j < 5; ++j) s = fmaf(w[j], Ab[j * 12 + mn], s);
      T[mn] = s;
    }
    float x = acc[i][0] + vt0, y = acc[i][1] + vt1, z = acc[i][2] + vt2;
    float ox = fmaf(T[0], x, fmaf(T[1], y, fmaf(T[2], z, T[3])));
    float oy = fmaf(T[4], x, fmaf(T[5], y, fmaf(T[6], z, T[7])));
    float oz = fmaf(T[8], x, fmaf(T[9], y, fmaf(T[10], z, T[11])));
    if (v < V_N) {
      size_t o = ((size_t)(b0 + i) * V_N + v) * 3;
      out[o + 0] = ox;
      out[o + 1] = oy;
      out[o + 2] = oz;
    }
  }
}

// ---------------- fallback (R1-proven, uncoalesced) ----------------
__global__ __launch_bounds__(256) void k_verts_fb(const float* __restrict__ sdirs,
                                                  const float* __restrict__ pdirs,
                                                  const float* __restrict__ vtemp,
                                                  const float* __restrict__ lw,
                                                  const float* __restrict__ bext,
                                                  const float* __restrict__ A,
                                                  float* __restrict__ out) {
  int t = threadIdx.x;
  int vl = t & 63;
  int wq = __builtin_amdgcn_readfirstlane(t >> 6);
  int v = blockIdx.x * 64 + vl;
  int b0 = blockIdx.y * 32 + wq * 8;
  if (v >= V_N) return;
  float acc[8][3];
#pragma unroll
  for (int i = 0; i < 8; ++i)
#pragma unroll
    for (int k = 0; k < 3; ++k) acc[i][k] = 0.0f;
  const float* sp = sdirs + (size_t)v * 450;
  const float* brow = bext + (size_t)b0 * BSTR;
  for (int l = 0; l < 150; l += 2) {
    float2 s0 = *reinterpret_cast<const float2*>(sp + l);
    float2 s1 = *reinterpret_cast<const float2*>(sp + 150 + l);
    float2 s2 = *reinterpret_cast<const float2*>(sp + 300 + l);
#pragma unroll
    for (int i = 0; i < 8; ++i) {
      float be0 = brow[i * BSTR + l];
      float be1 = brow[i * BSTR + l + 1];
      acc[i][0] = fmaf(s0.x, be0, fmaf(s0.y, be1, acc[i][0]));
      acc[i][1] = fmaf(s1.x, be0, fmaf(s1.y, be1, acc[i][1]));
      acc[i][2] = fmaf(s2.x, be0, fmaf(s2.y, be1, acc[i][2]));
    }
  }
  const float* pp = pdirs + (size_t)3 * v;
  for (int p = 0; p < 36; ++p) {
    float d0 = pp[(size_t)p * V3_N + 0];
    float d1 = pp[(size_t)p * V3_N + 1];
    float d2 = pp[(size_t)p * V3_N + 2];
#pragma unroll
    for (int i = 0; i < 8; ++i) {
      float pf = brow[i * BSTR + 150 + p];
      acc[i][0] = fmaf(d0, pf, acc[i][0]);
      acc[i][1] = fmaf(d1, pf, acc[i][1]);
      acc[i][2] = fmaf(d2, pf, acc[i][2]);
    }
  }
  float vt0 = vtemp[(size_t)v * 3 + 0];
  float vt1 = vtemp[(size_t)v * 3 + 1];
  float vt2 = vtemp[(size_t)v * 3 + 2];
  float w[5];
#pragma unroll
  for (int j = 0; j < 5; ++j) w[j] = lw[(size_t)v * 5 + j];
#pragma unroll
  for (int i = 0; i < 8; ++i) {
    const float* Ab = A + (size_t)(b0 + i) * 64;
    float T[12];
#pragma unroll
    for (int mn = 0; mn < 12; ++mn) {
      float s = w[0] * Ab[mn];
#pragma unroll
      for (int j = 1; j < 5; ++j) s = fmaf(w[j], Ab[j * 12 + mn], s);
      T[mn] = s;
    }
    float x = acc[i][0] + vt0, y = acc[i][1] + vt1, z = acc[i][2] + vt2;
    float ox = fmaf(T[0], x, fmaf(T[1], y, fmaf(T[2], z, T[3])));
    float oy = fmaf(T[4], x, fmaf(T[5], y, fmaf(T[6], z, T[7])));
    float oz = fmaf(T[8], x, fmaf(T[9], y, fmaf(T[10], z, T[11])));
    size_t o = ((size_t)(b0 + i) * V_N + v) * 3;
    out[o + 0] = ox;
    out[o + 1] = oy;
    out[o + 2] = oz;
  }
}

extern "C" void kernel_launch(void* const* d_in, const int* in_sizes, int n_in,
                              void* d_out, int out_size, void* d_ws, size_t ws_size,
                              hipStream_t stream) {
  const float* shp = (const float*)d_in[0];
  const float* expr = (const float*)d_in[1];
  const float* pose = (const float*)d_in[2];
  const float* vtemp = (const float*)d_in[3];
  const float* sdirs = (const float*)d_in[4];
  const float* pdirs = (const float*)d_in[5];
  const float* Jr = (const float*)d_in[6];
  const float* lw = (const float*)d_in[7];
  float* out = (float*)d_out;
  float* wsf = (float*)d_ws;

  // workspace layout (floats)
  const size_t OFF_PART = 0;                       // 157*2280 = 357,960
  const size_t OFF_SJ = 358400;                    // 2,280
  const size_t OFF_BEXT = 360704;                  // 2048*192 = 393,216
  const size_t OFF_JTS = 753920;                   // 2048*16  = 32,768
  const size_t OFF_A = 786688;                     // 2048*64  = 131,072
  const size_t OFF_BT = 917760;                    // 150*15069 = 2,260,350
  const size_t TOTAL_BT = OFF_BT + 2260352;        // ~12.7 MB
  float* part = wsf + OFF_PART;
  float* SJ = wsf + OFF_SJ;
  float* bext = wsf + OFF_BEXT;
  float* Jts = wsf + OFF_JTS;
  float* A = wsf + OFF_A;
  float* BT = wsf + OFF_BT;
  bool use_bt = (ws_size >= TOTAL_BT * sizeof(float));

  hipLaunchKernelGGL(k_sj_part, dim3(NSJB), dim3(256), 0, stream, sdirs, vtemp, Jr, part);
  hipLaunchKernelGGL(k_sj_reduce, dim3(9), dim3(256), 0, stream, part, SJ);
  hipLaunchKernelGGL(k_jts, dim3(128), dim3(256), 0, stream, shp, expr, SJ, Jts);
  hipLaunchKernelGGL(k_bext, dim3((B_N * BSTR + 255) / 256), dim3(256), 0, stream, shp, expr, bext);
  hipLaunchKernelGGL(k_pose, dim3(8), dim3(256), 0, stream, pose, Jts, bext, A, out);
  if (use_bt) {
    hipLaunchKernelGGL(k_trans, dim3((V_N + 15) / 16), dim3(256), 0, stream, sdirs, BT);
    hipLaunchKernelGGL(k_verts2, dim3(((V_N + 63) / 64) * 64), dim3(256), 0, stream,
                       BT, pdirs, vtemp, lw, bext, A, out);
  } else {
    hipLaunchKernelGGL(k_verts_fb, dim3((V_N + 63) / 64, B_N / 32), dim3(256), 0, stream,
                       sdirs, pdirs, vtemp, lw, bext, A, out);
  }
}

// Round 4
// 139.451 us; speedup vs baseline: 6.8249x; 2.1065x over previous
//
#include <hip/hip_runtime.h>
#include <hip/hip_bf16.h>
#include <math.h>

#define B_N 2048
#define V_N 5023
#define V3_N 15069
#define BSTR 192
#define NSJB 157
#define CHUNK 32
#define M4 20096  // padded vcomp4 rows = 314*64

typedef float f32x4 __attribute__((ext_vector_type(4)));
typedef short short8 __attribute__((ext_vector_type(8)));

static __device__ __forceinline__ ushort f2bf(float f) {
  __hip_bfloat16 h = __float2bfloat16(f);
  return *reinterpret_cast<ushort*>(&h);
}

// ---------------- K1: partial SJ[j][c] = sum_v Jr[j,v] * col_c(v) ----------------
__global__ __launch_bounds__(256) void k_sj_part(const float* __restrict__ sdirs,
                                                 const float* __restrict__ vtemp,
                                                 const float* __restrict__ Jr,
                                                 float* __restrict__ part) {
  __shared__ float JrL[5][CHUNK];
  int t = threadIdx.x, bk = blockIdx.x;
  int vstart = bk * CHUNK;
  int cnt = min(CHUNK, V_N - vstart);
  for (int idx = t; idx < 5 * CHUNK; idx += 256) {
    int j = idx / CHUNK, vi = idx % CHUNK;
    JrL[j][vi] = (vi < cnt) ? Jr[j * V_N + vstart + vi] : 0.0f;
  }
  __syncthreads();
  float acc0[5] = {0, 0, 0, 0, 0}, acc1[5] = {0, 0, 0, 0, 0};
  int c0 = t, c1 = t + 256;
#pragma unroll 4
  for (int vi = 0; vi < CHUNK; ++vi) {
    int v = min(vstart + vi, V_N - 1);
    float val0 = sdirs[(size_t)v * 450 + c0];
    float val1 = 0.0f;
    if (c1 < 450) val1 = sdirs[(size_t)v * 450 + c1];
    else if (c1 < 453) val1 = vtemp[(size_t)v * 3 + (c1 - 450)];
#pragma unroll
    for (int j = 0; j < 5; ++j) {
      float w = JrL[j][vi];
      acc0[j] = fmaf(w, val0, acc0[j]);
      acc1[j] = fmaf(w, val1, acc1[j]);
    }
  }
  float* prow = part + (size_t)bk * 2280;
#pragma unroll
  for (int j = 0; j < 5; ++j) {
    prow[j * 456 + c0] = acc0[j];
    if (c1 < 453) prow[j * 456 + c1] = acc1[j];
  }
}

__global__ void k_sj_reduce(const float* __restrict__ part, float* __restrict__ SJ) {
  int id = blockIdx.x * 256 + threadIdx.x;
  if (id >= 2280) return;
  int c = id % 456;
  if (c >= 453) return;
  float s = 0.0f;
  for (int bk = 0; bk < NSJB; ++bk) s += part[(size_t)bk * 2280 + id];
  SJ[id] = s;
}

__global__ void k_jts(const float* __restrict__ shp, const float* __restrict__ expr,
                      const float* __restrict__ SJ, float* __restrict__ Jts) {
  int gid = blockIdx.x * 256 + threadIdx.x;
  int b = gid >> 4, jk = gid & 15;
  if (b >= B_N || jk >= 15) return;
  int j = jk / 3, k = jk - j * 3;
  const float* SJr = SJ + j * 456;
  float acc = SJr[450 + k];
  const float* srow = shp + (size_t)b * 100;
  const float* erow = expr + (size_t)b * 50;
  for (int l = 0; l < 100; ++l) acc = fmaf(srow[l], SJr[k * 150 + l], acc);
  for (int l = 0; l < 50; ++l) acc = fmaf(erow[l], SJr[k * 150 + 100 + l], acc);
  Jts[(size_t)b * 16 + jk] = acc;
}

__global__ void k_bext(const float* __restrict__ shp, const float* __restrict__ expr,
                       float* __restrict__ bext) {
  int idx = blockIdx.x * 256 + threadIdx.x;
  if (idx >= B_N * BSTR) return;
  int b = idx / BSTR, c = idx - b * BSTR;
  float v = 0.0f;
  if (c < 100) v = shp[(size_t)b * 100 + c];
  else if (c < 150) v = expr[(size_t)b * 50 + (c - 100)];
  bext[idx] = v;
}

// ---------------- Rodrigues + kinematic chain + rel transforms ----------------
__global__ void k_pose(const float* __restrict__ pose, const float* __restrict__ Jts,
                       float* __restrict__ bext, float* __restrict__ A,
                       float* __restrict__ out) {
  int b = blockIdx.x * 256 + threadIdx.x;
  if (b >= B_N) return;
  float R[5][3][3];
#pragma unroll
  for (int j = 0; j < 5; ++j) {
    float rx = pose[(size_t)b * 15 + j * 3 + 0];
    float ry = pose[(size_t)b * 15 + j * 3 + 1];
    float rz = pose[(size_t)b * 15 + j * 3 + 2];
    float sx = rx + 1e-8f, sy = ry + 1e-8f, sz = rz + 1e-8f;
    float ang = sqrtf(sx * sx + sy * sy + sz * sz);
    float inv = 1.0f / ang;
    float ux = rx * inv, uy = ry * inv, uz = rz * inv;
    float c = cosf(ang), s = sinf(ang), omc = 1.0f - c;
    float K[3][3] = {{0.0f, -uz, uy}, {uz, 0.0f, -ux}, {-uy, ux, 0.0f}};
#pragma unroll
    for (int m = 0; m < 3; ++m)
#pragma unroll
      for (int n = 0; n < 3; ++n) {
        float k2 = 0.0f;
#pragma unroll
        for (int q = 0; q < 3; ++q) k2 += K[m][q] * K[q][n];
        R[j][m][n] = ((m == n) ? 1.0f : 0.0f) + s * K[m][n] + omc * k2;
      }
  }
  float* bx = bext + (size_t)b * BSTR + 150;
#pragma unroll
  for (int j = 1; j < 5; ++j)
#pragma unroll
    for (int m = 0; m < 3; ++m)
#pragma unroll
      for (int n = 0; n < 3; ++n)
        bx[(j - 1) * 9 + m * 3 + n] = R[j][m][n] - ((m == n) ? 1.0f : 0.0f);
  float Jt[5][3];
#pragma unroll
  for (int j = 0; j < 5; ++j)
#pragma unroll
    for (int k = 0; k < 3; ++k) Jt[j][k] = Jts[(size_t)b * 16 + j * 3 + k];
  const int par[5] = {0, 0, 1, 1, 1};
  float rel[5][3];
#pragma unroll
  for (int k = 0; k < 3; ++k) rel[0][k] = Jt[0][k];
#pragma unroll
  for (int j = 1; j < 5; ++j)
#pragma unroll
    for (int k = 0; k < 3; ++k) rel[j][k] = Jt[j][k] - Jt[par[j]][k];
  float Rg[5][3][3], tg[5][3];
#pragma unroll
  for (int m = 0; m < 3; ++m) {
#pragma unroll
    for (int n = 0; n < 3; ++n) Rg[0][m][n] = R[0][m][n];
    tg[0][m] = rel[0][m];
  }
#pragma unroll
  for (int j = 1; j < 5; ++j) {
    int p = par[j];
#pragma unroll
    for (int m = 0; m < 3; ++m) {
      float t = tg[p][m];
#pragma unroll
      for (int n = 0; n < 3; ++n) {
        float s = 0.0f;
#pragma unroll
        for (int q = 0; q < 3; ++q) s = fmaf(Rg[p][m][q], R[j][q][n], s);
        Rg[j][m][n] = s;
        t = fmaf(Rg[p][m][n], rel[j][n], t);
      }
      tg[j][m] = t;
    }
  }
#pragma unroll
  for (int j = 0; j < 5; ++j)
#pragma unroll
    for (int k = 0; k < 3; ++k)
      out[(size_t)B_N * V_N * 3 + ((size_t)b * 5 + j) * 3 + k] = tg[j][k];
  float* Ab = A + (size_t)b * 64;
#pragma unroll
  for (int j = 0; j < 5; ++j)
#pragma unroll
    for (int m = 0; m < 3; ++m) {
      float tj = 0.0f;
#pragma unroll
      for (int n = 0; n < 3; ++n) {
        Ab[j * 12 + m * 4 + n] = Rg[j][m][n];
        tj = fmaf(Rg[j][m][n], Jt[j][n], tj);
      }
      Ab[j * 12 + m * 4 + 3] = tg[j][m] - tj;
    }
}

// ---------------- convert bext f32 -> bf16 ----------------
__global__ void k_cvt(const float* __restrict__ bext, ushort* __restrict__ bb) {
  int idx = blockIdx.x * 256 + threadIdx.x;  // exactly 2048*96
  float f0 = bext[2 * idx], f1 = bext[2 * idx + 1];
  ((uint*)bb)[idx] = (uint)f2bf(f0) | ((uint)f2bf(f1) << 16);
}

// ---------------- build bf16 basis [M4=4*V pad][192] ----------------
// row = 4v+c: k<150 -> sdirs[v][c][k]; 150<=k<186 -> pdirs[k-150][3v+c]; else 0
__global__ __launch_bounds__(256) void k_basis(const float* __restrict__ sdirs,
                                               const float* __restrict__ pdirs,
                                               ushort* __restrict__ basis) {
  __shared__ float Sh[16][452];
  __shared__ float Pd[36][48];
  int t = threadIdx.x, bx = blockIdx.x;
  int v0 = bx * 16;
  for (int idx = t; idx < 16 * 450; idx += 256) {
    int r = idx / 450, c = idx - r * 450;
    int v = v0 + r;
    Sh[r][c] = (v < V_N) ? sdirs[(size_t)v * 450 + c] : 0.0f;
  }
  for (int idx = t; idx < 36 * 48; idx += 256) {
    int p = idx / 48, c = idx - p * 48;
    int v3 = v0 * 3 + c;
    Pd[p][c] = (v3 < V3_N) ? pdirs[(size_t)p * V3_N + v3] : 0.0f;
  }
  __syncthreads();
  for (int idx = t; idx < 64 * 96; idx += 256) {
    int row = idx / 96, kp = idx - row * 96;
    int vl = row >> 2, c = row & 3;
    int k0 = kp * 2;
    float f0 = 0.0f, f1 = 0.0f;
    if (c < 3) {
      if (k0 < 150) {
        f0 = Sh[vl][c * 150 + k0];
        f1 = Sh[vl][c * 150 + k0 + 1];
      } else if (k0 < 186) {
        f0 = Pd[k0 - 150][vl * 3 + c];
        f1 = Pd[k0 - 149][vl * 3 + c];
      }
    }
    uint u = (uint)f2bf(f0) | ((uint)f2bf(f1) << 16);
    ((uint*)basis)[(size_t)(bx * 64 + row) * 96 + kp] = u;
  }
}

// ---------------- main: MFMA GEMM (basis x bext^T) + fused skinning ----------------
// M = vcomp4 (64/block), N = batch (64/block), K = 192. 8 waves: 4(M) x 2(N).
__global__ __launch_bounds__(512, 4) void k_main(const ushort* __restrict__ basis,
                                                 const ushort* __restrict__ bb,
                                                 const float* __restrict__ Amat,
                                                 const float* __restrict__ lw,
                                                 const float* __restrict__ vtemp,
                                                 float* __restrict__ out) {
  __shared__ alignas(16) ushort AL[64 * 200];  // basis tile, rows padded to 200
  __shared__ alignas(16) ushort BL[64 * 200];  // bext tile
  __shared__ alignas(16) float AmL[64 * 68];   // rel-transforms, rows padded to 68
  int t = threadIdx.x;
  int bx = blockIdx.x, by = blockIdx.y;
  int b0 = by * 64;
  // stage basis + bext tiles: 64 rows x 192 bf16 = 1536 16B-chunks each
#pragma unroll
  for (int i = 0; i < 3; ++i) {
    int c = t + i * 512;
    int r = c / 24, k = (c % 24) * 8;
    *(short8*)(&AL[r * 200 + k]) = *(const short8*)(&basis[((size_t)bx * 64 + r) * 192 + k]);
    *(short8*)(&BL[r * 200 + k]) = *(const short8*)(&bb[((size_t)(b0 + r)) * 192 + k]);
  }
  // stage Amat: 64 rows x 64 f32 = 1024 16B-chunks
#pragma unroll
  for (int i = 0; i < 2; ++i) {
    int c = t + i * 512;
    int r = c / 16, q = (c % 16) * 4;
    *(f32x4*)(&AmL[r * 68 + q]) = *(const f32x4*)(&Amat[((size_t)(b0 + r)) * 64 + q]);
  }
  __syncthreads();
  int lane = t & 63;
  int w = __builtin_amdgcn_readfirstlane(t >> 6);
  int wm = w >> 1, wn = w & 1;
  int lm = lane & 15, g = lane >> 4;
  f32x4 acc0 = {0.f, 0.f, 0.f, 0.f}, acc1 = {0.f, 0.f, 0.f, 0.f};
  const int arow = (wm * 16 + lm) * 200;
  const int brow0 = (wn * 32 + lm) * 200;
  const int brow1 = (wn * 32 + 16 + lm) * 200;
#pragma unroll
  for (int ks = 0; ks < 6; ++ks) {
    int k = ks * 32 + 8 * g;
    short8 af = *(const short8*)(&AL[arow + k]);
    short8 bf0 = *(const short8*)(&BL[brow0 + k]);
    short8 bf1 = *(const short8*)(&BL[brow1 + k]);
    acc0 = __builtin_amdgcn_mfma_f32_16x16x32_bf16(af, bf0, acc0, 0, 0, 0);
    acc1 = __builtin_amdgcn_mfma_f32_16x16x32_bf16(af, bf1, acc1, 0, 0, 0);
  }
  // epilogue: lane-local vertex v (comps in acc regs 0..2), 2 batches
  int v = bx * 16 + wm * 4 + g;
  bool valid = v < V_N;
  int vv = valid ? v : 0;
  float wj[5];
#pragma unroll
  for (int j = 0; j < 5; ++j) wj[j] = lw[(size_t)vv * 5 + j];
  float vt0 = vtemp[(size_t)vv * 3 + 0];
  float vt1 = vtemp[(size_t)vv * 3 + 1];
  float vt2 = vtemp[(size_t)vv * 3 + 2];
#pragma unroll
  for (int ni = 0; ni < 2; ++ni) {
    f32x4 p = ni ? acc1 : acc0;
    int bl = wn * 32 + ni * 16 + lm;
    const float* Ar = &AmL[bl * 68];
    f32x4 T0 = {0.f, 0.f, 0.f, 0.f}, T1 = {0.f, 0.f, 0.f, 0.f}, T2 = {0.f, 0.f, 0.f, 0.f};
#pragma unroll
    for (int j = 0; j < 5; ++j) {
      f32x4 a0 = *(const f32x4*)(Ar + j * 12 + 0);
      f32x4 a1 = *(const f32x4*)(Ar + j * 12 + 4);
      f32x4 a2 = *(const f32x4*)(Ar + j * 12 + 8);
#pragma unroll
      for (int c = 0; c < 4; ++c) {
        T0[c] = fmaf(wj[j], a0[c], T0[c]);
        T1[c] = fmaf(wj[j], a1[c], T1[c]);
        T2[c] = fmaf(wj[j], a2[c], T2[c]);
      }
    }
    float x = p[0] + vt0, y = p[1] + vt1, z = p[2] + vt2;
    float ox = fmaf(T0[0], x, fmaf(T0[1], y, fmaf(T0[2], z, T0[3])));
    float oy = fmaf(T1[0], x, fmaf(T1[1], y, fmaf(T1[2], z, T1[3])));
    float oz = fmaf(T2[0], x, fmaf(T2[1], y, fmaf(T2[2], z, T2[3])));
    if (valid) {
      size_t o = ((size_t)(b0 + bl)) * V3_N + (size_t)v * 3;
      out[o + 0] = ox;
      out[o + 1] = oy;
      out[o + 2] = oz;
    }
  }
}

extern "C" void kernel_launch(void* const* d_in, const int* in_sizes, int n_in,
                              void* d_out, int out_size, void* d_ws, size_t ws_size,
                              hipStream_t stream) {
  const float* shp = (const float*)d_in[0];
  const float* expr = (const float*)d_in[1];
  const float* pose = (const float*)d_in[2];
  const float* vtemp = (const float*)d_in[3];
  const float* sdirs = (const float*)d_in[4];
  const float* pdirs = (const float*)d_in[5];
  const float* Jr = (const float*)d_in[6];
  const float* lw = (const float*)d_in[7];
  float* out = (float*)d_out;
  float* wsf = (float*)d_ws;

  // workspace layout (float slots)
  const size_t OFF_PART = 0;         // 157*2280 = 357,960
  const size_t OFF_SJ = 358400;      // 2,280
  const size_t OFF_BEXT = 360704;    // 2048*192 = 393,216
  const size_t OFF_JTS = 753920;     // 32,768
  const size_t OFF_A = 786688;       // 131,072
  const size_t OFF_BB = 917760;      // bf16 2048*192 = 393,216 bf16 -> 196,608 f32 slots
  const size_t OFF_BASIS = 1114368;  // bf16 20096*192 -> 1,929,216 f32 slots (ends 3,043,584)
  float* part = wsf + OFF_PART;
  float* SJ = wsf + OFF_SJ;
  float* bext = wsf + OFF_BEXT;
  float* Jts = wsf + OFF_JTS;
  float* A = wsf + OFF_A;
  ushort* bb = (ushort*)(wsf + OFF_BB);
  ushort* basis = (ushort*)(wsf + OFF_BASIS);

  hipLaunchKernelGGL(k_basis, dim3(314), dim3(256), 0, stream, sdirs, pdirs, basis);
  hipLaunchKernelGGL(k_sj_part, dim3(NSJB), dim3(256), 0, stream, sdirs, vtemp, Jr, part);
  hipLaunchKernelGGL(k_sj_reduce, dim3(9), dim3(256), 0, stream, part, SJ);
  hipLaunchKernelGGL(k_jts, dim3(128), dim3(256), 0, stream, shp, expr, SJ, Jts);
  hipLaunchKernelGGL(k_bext, dim3((B_N * BSTR + 255) / 256), dim3(256), 0, stream, shp, expr, bext);
  hipLaunchKernelGGL(k_pose, dim3(8), dim3(256), 0, stream, pose, Jts, bext, A, out);
  hipLaunchKernelGGL(k_cvt, dim3(768), dim3(256), 0, stream, bext, bb);
  hipLaunchKernelGGL(k_main, dim3(314, 32), dim3(512), 0, stream,
                     basis, bb, A, lw, vtemp, out);
}